// Round 10
// baseline (900.566 us; speedup 1.0000x reference)
//
#include <hip/hip_runtime.h>
#include <hip/hip_bf16.h>

// Problem constants (B, D, DOUT from reference)
#define BDIM 8192
#define DDIM 4096
#define DOUTD 4096

typedef __attribute__((ext_vector_type(8))) short short8;
typedef __attribute__((ext_vector_type(4))) float floatx4;

// round-to-nearest-even fp32 -> bf16 (bit pattern)
__device__ inline unsigned short f32_to_bf16_rne(float f) {
    unsigned int u = __float_as_uint(f);
    unsigned int lsb = (u >> 16) & 1u;
    u += 0x7fffu + lsb;
    return (unsigned short)(u >> 16);
}

// async global->LDS, 16B per lane; lds base must be wave-uniform
__device__ inline void gload_lds16(const void* g, void* lds) {
    __builtin_amdgcn_global_load_lds(
        (const __attribute__((address_space(1))) void*)g,
        (__attribute__((address_space(3))) void*)lds,
        16, 0, 0);
}

// Convert x (fp32 [B,D]) to bf16 natural (xb [B,D]) and transposed (xT [D,B]).
__global__ __launch_bounds__(256)
void convert_transpose_x(const float* __restrict__ x,
                         unsigned short* __restrict__ xb,
                         unsigned short* __restrict__ xT) {
    __shared__ __align__(8) unsigned short tile[64][66];  // [b][d], +2 pad
    const int t = threadIdx.x;
    const int tb = blockIdx.x * 64;   // b offset
    const int td = blockIdx.y * 64;   // d offset
#pragma unroll
    for (int p = 0; p < 4; ++p) {
        int c = t + p * 256;            // [0,1024)
        int row  = c >> 4;              // b-local
        int col4 = (c & 15) << 2;       // d-local
        float4 v = *(const float4*)&x[(size_t)(tb + row) * DDIM + td + col4];
        ushort4 o;
        o.x = f32_to_bf16_rne(v.x);
        o.y = f32_to_bf16_rne(v.y);
        o.z = f32_to_bf16_rne(v.z);
        o.w = f32_to_bf16_rne(v.w);
        *(ushort4*)&xb[(size_t)(tb + row) * DDIM + td + col4] = o;
        ushort2 lo; lo.x = o.x; lo.y = o.y;
        ushort2 hi2; hi2.x = o.z; hi2.y = o.w;
        *(ushort2*)&tile[row][col4]     = lo;
        *(ushort2*)&tile[row][col4 + 2] = hi2;
    }
    __syncthreads();
#pragma unroll
    for (int p = 0; p < 4; ++p) {
        int c = t + p * 256;
        int drow = c >> 4;              // d-local
        int b4   = (c & 15) << 2;       // b-local
        ushort4 o;
        o.x = tile[b4 + 0][drow];
        o.y = tile[b4 + 1][drow];
        o.z = tile[b4 + 2][drow];
        o.w = tile[b4 + 3][drow];
        *(ushort4*)&xT[(size_t)(td + drow) * BDIM + tb + b4] = o;
    }
}

// Elementwise fp32 -> bf16 for W (8 elems/thread, 16B writes)
__global__ __launch_bounds__(256)
void convert_w_kernel(const float* __restrict__ W, unsigned short* __restrict__ Wb) {
    size_t i = ((size_t)blockIdx.x * 256 + threadIdx.x) * 8;
    float4 a = *(const float4*)&W[i];
    float4 b = *(const float4*)&W[i + 4];
    short8 o;
    o[0] = (short)f32_to_bf16_rne(a.x);
    o[1] = (short)f32_to_bf16_rne(a.y);
    o[2] = (short)f32_to_bf16_rne(a.z);
    o[3] = (short)f32_to_bf16_rne(a.w);
    o[4] = (short)f32_to_bf16_rne(b.x);
    o[5] = (short)f32_to_bf16_rne(b.y);
    o[6] = (short)f32_to_bf16_rne(b.z);
    o[7] = (short)f32_to_bf16_rne(b.w);
    *(short8*)&Wb[i] = o;
}

// compiler memory fence (zero instructions) + raw barrier
#define CFENCE() asm volatile("" ::: "memory")
#define BAR() do { CFENCE(); __builtin_amdgcn_s_barrier(); CFENCE(); } while (0)
#define MFMA16 __builtin_amdgcn_mfma_f32_16x16x32_bf16

// ---------------------------------------------------------------------------
// C[m,n] = sum_k A[m,k]*B[n,k]  (+ bias[n]  or  + eps on diagonal)
// A: [M,K] bf16 row-major, B: [N,K] bf16 row-major, C: [M,N] fp32.
//
// v10 = verified v2 skeleton (quadrant phases, reads 12/8/4/0, stage mapping,
// vmcnt ledger, zero-conflict swizzle -- all unchanged) with the MFMA shape
// swapped 32x32x16 -> 16x16x32 (m201's shape): 16 MFMAs/phase as 8
// independent chains of length 2 (~19.4 cyc/SIMD granules vs 32.3),
// the regime where cross-wave LDS-drain || MFMA overlap engages.
//
// Frag layout (16x16x32, m89-verified): A lane l: row l&15, k=(l>>4)*8..+8;
// B lane l: col l&15, same k. C/D: col=lane&15, row=(lane>>4)*4+reg.
// Frag read (mf,ks): As[AB + ks*8192 + (wm*128+mf*16+l15)*32 + pofs],
// pofs = ((lq ^ ((l15>>2)&3))<<3), lq=lane>>4 -- the row-key is mf-invariant
// so ONE pofs serves all frags. Bank check: 16 rows x 4 lq -> stored pos
// p = lq^key(row); banks 16*(row&1)+4p+d covered exactly 2x (2-way = free).
//
// Phases (v2 mapping, WAR-clean: no same-phase same-array read+stage):
//  P1: read bf qn0 (4) + af0 mf0-3 (8); stage Bh1(J+1)->buf^1;
//      BAR; MFMA acc[0..3][0..1] (qn0) ks0,ks1; lgkm(0); BAR.
//  P2: read af1 mf4-7 (8); stage Bh0(J+2)->buf;
//      BAR; MFMA acc[4..7][0..1]; lgkm(0); BAR.
//  P3: read bf qn1 (4); stage Ah0(J+2)->buf;
//      BAR; MFMA acc[4..7][2..3]; lgkm(0); BAR.
//  P4: stage Ah1(J+2)->buf; BAR; MFMA acc[0..3][2..3]; vmcnt(6|0); BAR.
// Ledger identical to v2: prologue 7 stages -> vmcnt(6); steady-state
// 14 outstanding at end-P4, vmcnt(6) retires exactly tile j+1's 8.
// ---------------------------------------------------------------------------
template <bool HESS>
__global__ __launch_bounds__(512, 2)
void gemm256(const unsigned short* __restrict__ A,
             const unsigned short* __restrict__ B,
             const float* __restrict__ bias,
             float* __restrict__ C,
             int M, int N, int K) {
    __shared__ __align__(16) unsigned short As[32768];  // 2 buf x 2 region x 256 x 32
    __shared__ __align__(16) unsigned short Bs[32768];

    const int t    = threadIdx.x;
    const int lane = t & 63;
    const int w    = t >> 6;          // wave 0..7
    const int l15  = lane & 15;
    const int lq   = lane >> 4;       // 0..3: k-subgroup (A/B), row-subgroup (C/D)
    const int wm   = w >> 2;          // 0..1  (M half of block tile)
    const int wn   = w & 3;           // 0..3  (N quarter)
    const size_t bm = (size_t)blockIdx.y * 256;
    const size_t bn = (size_t)blockIdx.x * 256;
    const int NT = K >> 6;            // K-tiles (even: 64 or 128 here)

    // ---- staging source pointers (per lane), inverse-swizzled k chunk ----
    const int kh_w = w >> 2;          // which 64B k-half this wave stages
    const int wq   = w & 3;           // 2KB stripe within (half-tile, region)
    const int rsub = lane >> 2;       // row within 16-row stripe
    const int csrc = (lane & 3) ^ ((lane >> 4) & 3);  // global k-chunk (of 4)
    const unsigned short* gA0 = A + (bm + wq * 32 + rsub) * (size_t)K + kh_w * 32 + csrc * 8;
    const unsigned short* gB0 = B + (bn + wq * 32 + rsub) * (size_t)K + kh_w * 32 + csrc * 8;
    char* ldsA = (char*)As + kh_w * 16384 + wq * 2048;  // + buf*32768 + h*8192
    char* ldsB = (char*)Bs + kh_w * 16384 + wq * 2048;
    const size_t rowK16 = (size_t)16 * K;   // 16 rows (shorts)
    const size_t halfK  = (size_t)128 * K;  // half-tile row jump (shorts)

#define STAGE_A(tj, h, buf) do {                                   \
        const size_t _ko = (size_t)(tj) * 64 + (size_t)(h) * halfK;\
        char* _d = ldsA + (buf) * 32768 + (h) * 8192;              \
        gload_lds16(gA0 + _ko, _d);                                \
        gload_lds16(gA0 + _ko + rowK16, _d + 1024);                \
    } while (0)
#define STAGE_B(tj, h, buf) do {                                   \
        const size_t _ko = (size_t)(tj) * 64 + (size_t)(h) * halfK;\
        char* _d = ldsB + (buf) * 32768 + (h) * 8192;              \
        gload_lds16(gB0 + _ko, _d);                                \
        gload_lds16(gB0 + _ko + rowK16, _d + 1024);                \
    } while (0)

    // ---- read offsets (shorts) ----
    // frag (row R, ks): addr = AB + ks*8192 + R*32 + pofs
    const int pofs  = ((lq ^ ((l15 >> 2) & 3)) << 3);
    const int AROW0 = (wm * 128 + l15) * 32 + pofs;   // + mf*512 + ks*8192
    const int BROW0 = (wn * 32 + l15) * 32 + pofs;    // + qn*4096 + nf*512 + ks*8192

    floatx4 acc[8][4];   // [mf][qn*2+nf]
#pragma unroll
    for (int i = 0; i < 8; ++i)
#pragma unroll
        for (int j = 0; j < 4; ++j)
#pragma unroll
            for (int g = 0; g < 4; ++g)
                acc[i][j][g] = 0.f;

    short8 af0[4][2], af1[4][2], bfr[2][2];   // [mf][ks] / [nf][ks]

#define TILE_BODY(J, BUFC) do {                                            \
        constexpr int AB = (BUFC) * 16384;                                 \
        /* -- P1: read bf qn0 + af0 mf0-3; stage Bh1(J+1)->buf^1 -- */     \
        _Pragma("unroll")                                                  \
        for (int nf = 0; nf < 2; ++nf)                                     \
            _Pragma("unroll")                                              \
            for (int ks = 0; ks < 2; ++ks)                                 \
                bfr[nf][ks] = *(const short8*)&Bs[AB + ks * 8192 + BROW0 + nf * 512]; \
        _Pragma("unroll")                                                  \
        for (int mf = 0; mf < 4; ++mf)                                     \
            _Pragma("unroll")                                              \
            for (int ks = 0; ks < 2; ++ks)                                 \
                af0[mf][ks] = *(const short8*)&As[AB + ks * 8192 + AROW0 + mf * 512]; \
        if ((J) + 1 < NT) STAGE_B((J) + 1, 1, (BUFC) ^ 1);                 \
        BAR();                                                             \
        __builtin_amdgcn_s_setprio(1);                                     \
        _Pragma("unroll")                                                  \
        for (int ks = 0; ks < 2; ++ks)                                     \
            _Pragma("unroll")                                              \
            for (int nf = 0; nf < 2; ++nf)                                 \
                _Pragma("unroll")                                          \
                for (int mf = 0; mf < 4; ++mf)                             \
                    acc[mf][nf] = MFMA16(af0[mf][ks], bfr[nf][ks], acc[mf][nf], 0, 0, 0); \
        __builtin_amdgcn_s_setprio(0);                                     \
        asm volatile("s_waitcnt lgkmcnt(0)" ::: "memory");                 \
        BAR();                                                             \
        /* -- P2: read af1 mf4-7; stage Bh0(J+2)->buf -- */                \
        _Pragma("unroll")                                                  \
        for (int mf = 0; mf < 4; ++mf)                                     \
            _Pragma("unroll")                                              \
            for (int ks = 0; ks < 2; ++ks)                                 \
                af1[mf][ks] = *(const short8*)&As[AB + ks * 8192 + AROW0 + (4 + mf) * 512]; \
        if ((J) + 2 < NT) STAGE_B((J) + 2, 0, (BUFC));                     \
        BAR();                                                             \
        __builtin_amdgcn_s_setprio(1);                                     \
        _Pragma("unroll")                                                  \
        for (int ks = 0; ks < 2; ++ks)                                     \
            _Pragma("unroll")                                              \
            for (int nf = 0; nf < 2; ++nf)                                 \
                _Pragma("unroll")                                          \
                for (int mf = 0; mf < 4; ++mf)                             \
                    acc[4 + mf][nf] = MFMA16(af1[mf][ks], bfr[nf][ks], acc[4 + mf][nf], 0, 0, 0); \
        __builtin_amdgcn_s_setprio(0);                                     \
        asm volatile("s_waitcnt lgkmcnt(0)" ::: "memory");                 \
        BAR();                                                             \
        /* -- P3: read bf qn1; stage Ah0(J+2)->buf -- */                   \
        _Pragma("unroll")                                                  \
        for (int nf = 0; nf < 2; ++nf)                                     \
            _Pragma("unroll")                                              \
            for (int ks = 0; ks < 2; ++ks)                                 \
                bfr[nf][ks] = *(const short8*)&Bs[AB + ks * 8192 + BROW0 + 4096 + nf * 512]; \
        if ((J) + 2 < NT) STAGE_A((J) + 2, 0, (BUFC));                     \
        BAR();                                                             \
        __builtin_amdgcn_s_setprio(1);                                     \
        _Pragma("unroll")                                                  \
        for (int ks = 0; ks < 2; ++ks)                                     \
            _Pragma("unroll")                                              \
            for (int nf = 0; nf < 2; ++nf)                                 \
                _Pragma("unroll")                                          \
                for (int mf = 0; mf < 4; ++mf)                             \
                    acc[4 + mf][2 + nf] = MFMA16(af1[mf][ks], bfr[nf][ks], acc[4 + mf][2 + nf], 0, 0, 0); \
        __builtin_amdgcn_s_setprio(0);                                     \
        asm volatile("s_waitcnt lgkmcnt(0)" ::: "memory");                 \
        BAR();                                                             \
        /* -- P4: stage Ah1(J+2)->buf; MFMA qn1 x mf0-3; vmcnt drain -- */ \
        if ((J) + 2 < NT) STAGE_A((J) + 2, 1, (BUFC));                     \
        BAR();                                                             \
        __builtin_amdgcn_s_setprio(1);                                     \
        _Pragma("unroll")                                                  \
        for (int ks = 0; ks < 2; ++ks)                                     \
            _Pragma("unroll")                                              \
            for (int nf = 0; nf < 2; ++nf)                                 \
                _Pragma("unroll")                                          \
                for (int mf = 0; mf < 4; ++mf)                             \
                    acc[mf][2 + nf] = MFMA16(af0[mf][ks], bfr[nf][ks], acc[mf][2 + nf], 0, 0, 0); \
        __builtin_amdgcn_s_setprio(0);                                     \
        if ((J) < NT - 2)       asm volatile("s_waitcnt vmcnt(6)" ::: "memory"); \
        else if ((J) == NT - 2) asm volatile("s_waitcnt vmcnt(0)" ::: "memory"); \
        BAR();                                                             \
    } while (0)

    // ---- prologue: tile0 full + tile1 {Bh0,Ah0,Ah1}; drain tile0 ----
    STAGE_B(0, 0, 0); STAGE_A(0, 0, 0); STAGE_A(0, 1, 0); STAGE_B(0, 1, 0);
    STAGE_B(1, 0, 1); STAGE_A(1, 0, 1); STAGE_A(1, 1, 1);
    asm volatile("s_waitcnt vmcnt(6)" ::: "memory");
    BAR();

    for (int jj = 0; jj < NT; jj += 2) {
        TILE_BODY(jj, 0);
        TILE_BODY(jj + 1, 1);
    }
#undef STAGE_A
#undef STAGE_B
#undef TILE_BODY

    // ---- epilogue: 16x16 D layout: col = lane&15 (n), row = lq*4 + reg (m)
    float bv[4];
#pragma unroll
    for (int q = 0; q < 4; ++q)
        bv[q] = HESS ? 0.f : bias[bn + (q >> 1) * 128 + wn * 32 + (q & 1) * 16 + l15];
#pragma unroll
    for (int mf = 0; mf < 8; ++mf) {
        const size_t mbase = bm + wm * 128 + mf * 16 + lq * 4;
#pragma unroll
        for (int q = 0; q < 4; ++q) {
            const size_t n = bn + (q >> 1) * 128 + wn * 32 + (q & 1) * 16 + l15;
#pragma unroll
            for (int reg = 0; reg < 4; ++reg) {
                const size_t m = mbase + reg;
                float v = acc[mf][q][reg] + bv[q];
                if (HESS && m == n) v += 1e-4f;
                C[m * N + n] = v;
            }
        }
    }
}

extern "C" void kernel_launch(void* const* d_in, const int* in_sizes, int n_in,
                              void* d_out, int out_size, void* d_ws, size_t ws_size,
                              hipStream_t stream) {
    const float* x = (const float*)d_in[0];   // [8192, 4096]
    const float* W = (const float*)d_in[1];   // [4096, 4096]
    const float* b = (const float*)d_in[2];   // [4096]

    float* out  = (float*)d_out;                       // [8192, 4096]
    float* hess = out + (size_t)BDIM * DOUTD;          // [4096, 4096]

    // workspace layout (bf16): xb [B,D] | xT [D,B] | Wb [DOUT,D]  = 168 MB
    unsigned short* xb = (unsigned short*)d_ws;
    unsigned short* xT = xb + (size_t)BDIM * DDIM;
    unsigned short* Wb = xT + (size_t)BDIM * DDIM;

    convert_transpose_x<<<dim3(BDIM / 64, DDIM / 64), 256, 0, stream>>>(x, xb, xT);
    convert_w_kernel<<<((size_t)DOUTD * DDIM) / 2048, 256, 0, stream>>>(W, Wb);

    // out = x @ W.T + b : M=8192, N=4096, K=4096  (grid 16 x 32 = 512 blocks)
    gemm256<false><<<dim3(DOUTD / 256, BDIM / 256), 512, 0, stream>>>(
        xb, Wb, b, out, BDIM, DOUTD, DDIM);
    // hess = xT @ xT.T + eps*I : M=N=4096, K=8192  (grid 16 x 16 = 256 blocks)
    gemm256<true><<<dim3(DDIM / 256, DDIM / 256), 512, 0, stream>>>(
        xT, xT, nullptr, hess, DDIM, DDIM, BDIM);
}

// Round 11
// 889.493 us; speedup vs baseline: 1.0124x; 1.0124x over previous
//
#include <hip/hip_runtime.h>
#include <hip/hip_bf16.h>

// Problem constants (B, D, DOUT from reference)
#define BDIM 8192
#define DDIM 4096
#define DOUTD 4096

typedef __attribute__((ext_vector_type(8))) short short8;
typedef __attribute__((ext_vector_type(16))) float floatx16;

// round-to-nearest-even fp32 -> bf16 (bit pattern)
__device__ inline unsigned short f32_to_bf16_rne(float f) {
    unsigned int u = __float_as_uint(f);
    unsigned int lsb = (u >> 16) & 1u;
    u += 0x7fffu + lsb;
    return (unsigned short)(u >> 16);
}

// async global->LDS, 16B per lane; lds base must be wave-uniform
__device__ inline void gload_lds16(const void* g, void* lds) {
    __builtin_amdgcn_global_load_lds(
        (const __attribute__((address_space(1))) void*)g,
        (__attribute__((address_space(3))) void*)lds,
        16, 0, 0);
}

// Convert x (fp32 [B,D]) to bf16 natural (xb [B,D]) and transposed (xT [D,B]).
__global__ __launch_bounds__(256)
void convert_transpose_x(const float* __restrict__ x,
                         unsigned short* __restrict__ xb,
                         unsigned short* __restrict__ xT) {
    __shared__ __align__(8) unsigned short tile[64][66];  // [b][d], +2 pad
    const int t = threadIdx.x;
    const int tb = blockIdx.x * 64;   // b offset
    const int td = blockIdx.y * 64;   // d offset
#pragma unroll
    for (int p = 0; p < 4; ++p) {
        int c = t + p * 256;            // [0,1024)
        int row  = c >> 4;              // b-local
        int col4 = (c & 15) << 2;       // d-local
        float4 v = *(const float4*)&x[(size_t)(tb + row) * DDIM + td + col4];
        ushort4 o;
        o.x = f32_to_bf16_rne(v.x);
        o.y = f32_to_bf16_rne(v.y);
        o.z = f32_to_bf16_rne(v.z);
        o.w = f32_to_bf16_rne(v.w);
        *(ushort4*)&xb[(size_t)(tb + row) * DDIM + td + col4] = o;
        ushort2 lo; lo.x = o.x; lo.y = o.y;
        ushort2 hi2; hi2.x = o.z; hi2.y = o.w;
        *(ushort2*)&tile[row][col4]     = lo;
        *(ushort2*)&tile[row][col4 + 2] = hi2;
    }
    __syncthreads();
#pragma unroll
    for (int p = 0; p < 4; ++p) {
        int c = t + p * 256;
        int drow = c >> 4;              // d-local
        int b4   = (c & 15) << 2;       // b-local
        ushort4 o;
        o.x = tile[b4 + 0][drow];
        o.y = tile[b4 + 1][drow];
        o.z = tile[b4 + 2][drow];
        o.w = tile[b4 + 3][drow];
        *(ushort4*)&xT[(size_t)(td + drow) * BDIM + tb + b4] = o;
    }
}

// Elementwise fp32 -> bf16 for W (8 elems/thread, 16B writes)
__global__ __launch_bounds__(256)
void convert_w_kernel(const float* __restrict__ W, unsigned short* __restrict__ Wb) {
    size_t i = ((size_t)blockIdx.x * 256 + threadIdx.x) * 8;
    float4 a = *(const float4*)&W[i];
    float4 b = *(const float4*)&W[i + 4];
    short8 o;
    o[0] = (short)f32_to_bf16_rne(a.x);
    o[1] = (short)f32_to_bf16_rne(a.y);
    o[2] = (short)f32_to_bf16_rne(a.z);
    o[3] = (short)f32_to_bf16_rne(a.w);
    o[4] = (short)f32_to_bf16_rne(b.x);
    o[5] = (short)f32_to_bf16_rne(b.y);
    o[6] = (short)f32_to_bf16_rne(b.z);
    o[7] = (short)f32_to_bf16_rne(b.w);
    *(short8*)&Wb[i] = o;
}

// compiler memory fence (zero instructions) + raw barrier
#define CFENCE() asm volatile("" ::: "memory")
#define BAR() do { CFENCE(); __builtin_amdgcn_s_barrier(); CFENCE(); } while (0)
#define MFMA_BF16 __builtin_amdgcn_mfma_f32_32x32x16_bf16

// ---------------------------------------------------------------------------
// GEMM: inner loop byte-identical to round-8 v8 (best verified: 857us total,
// 0 bank conflicts). One addition: bijective XCD-aware block swizzle.
//
// Rationale (round-10 theory): all schedule variants pin at 37-43% MfmaUtil
// because operand staging needs ~19 TB/s aggregate at MFMA peak but the
// L2-miss/L3 path delivers ~6.8 TB/s. Default dispatch round-robins blocks
// over 8 XCDs (XCD = linear%8), so e.g. gemm1's 64 blocks/XCD span 32 A-
// panels + 2 B-panels (~1.1MB/K-slice working set). Remapping each XCD to a
// contiguous band (wgid = (l%8)*(nwg/8) + l/8; both grids %8==0 so this is
// bijective, m204) gives 4 A + 16 B panels (640KB) -> better L2 reuse,
// less L3 traffic. Observable signature: FETCH_SIZE drop.
//
// C[m,n] = sum_k A[m,k]*B[n,k]  (+ bias[n]  or  + eps on diagonal)
// 256x256 tile, BK=64, 512 threads = 8 waves (2M x 4N), wave tile 128x64.
// Phases of 4 independent chains of length 2; reads 6/8/4/6 per phase;
// stage Bh1(j+1)|Bh0(j+2)|Ah0(j+2)|Ah1(j+2) at P1..P4; vmcnt(6) at P4 entry
// (vmcnt(0) at j==NT-2); early reads for next tile at end of P4 (post-MFMA,
// post-drain-BAR). LDS [region(2)x16KB][row(256)x64B][p(4)x16B chunks],
// chunk p = c2 ^ ((row>>2)&3) (zero-conflict, measured).
// ---------------------------------------------------------------------------
template <bool HESS>
__global__ __launch_bounds__(512, 2)
void gemm256(const unsigned short* __restrict__ A,
             const unsigned short* __restrict__ B,
             const float* __restrict__ bias,
             float* __restrict__ C,
             int M, int N, int K) {
    __shared__ __align__(16) unsigned short As[32768];  // 2 buf x 2 region x 256 x 32
    __shared__ __align__(16) unsigned short Bs[32768];

    const int t    = threadIdx.x;
    const int lane = t & 63;
    const int w    = t >> 6;          // wave 0..7
    const int lm   = lane & 31;
    const int hi   = lane >> 5;       // k-half within MFMA operand
    const int key2 = (lm >> 2) & 3;   // read-side swizzle key (rows 32-aligned)
    const int wm   = w >> 2;          // 0..1  (M half of block tile)
    const int wn   = w & 3;           // 0..3  (N quarter)

    // ---- bijective XCD-aware block swizzle (nwg % 8 == 0 for both grids) --
    const int nwg  = gridDim.x * gridDim.y;
    const int lin  = blockIdx.y * gridDim.x + blockIdx.x;  // dispatch order
    const int wgid = (lin & 7) * (nwg >> 3) + (lin >> 3);  // XCD -> contiguous band
    const int bx2  = wgid % gridDim.x;
    const int by2  = wgid / gridDim.x;
    const size_t bm = (size_t)by2 * 256;
    const size_t bn = (size_t)bx2 * 256;
    const int NT = K >> 6;            // K-tiles (even: 64 or 128 here)

    // ---- staging source pointers (per lane), inverse-swizzled k chunk ----
    const int kh_w = w >> 2;          // which 64B k-half this wave stages
    const int wq   = w & 3;           // 2KB stripe within (half-tile, region)
    const int rsub = lane >> 2;       // row within 16-row stripe
    const int csrc = (lane & 3) ^ ((lane >> 4) & 3);  // global k-chunk (of 4)
    const unsigned short* gA0 = A + (bm + wq * 32 + rsub) * (size_t)K + kh_w * 32 + csrc * 8;
    const unsigned short* gB0 = B + (bn + wq * 32 + rsub) * (size_t)K + kh_w * 32 + csrc * 8;
    char* ldsA = (char*)As + kh_w * 16384 + wq * 2048;  // + buf*32768 + h*8192
    char* ldsB = (char*)Bs + kh_w * 16384 + wq * 2048;
    const size_t rowK16 = (size_t)16 * K;   // 16 rows (shorts)
    const size_t halfK  = (size_t)128 * K;  // half-tile row jump (shorts)

#define STAGE_A(tj, h, buf) do {                                   \
        const size_t _ko = (size_t)(tj) * 64 + (size_t)(h) * halfK;\
        char* _d = ldsA + (buf) * 32768 + (h) * 8192;              \
        gload_lds16(gA0 + _ko, _d);                                \
        gload_lds16(gA0 + _ko + rowK16, _d + 1024);                \
    } while (0)
#define STAGE_B(tj, h, buf) do {                                   \
        const size_t _ko = (size_t)(tj) * 64 + (size_t)(h) * halfK;\
        char* _d = ldsB + (buf) * 32768 + (h) * 8192;              \
        gload_lds16(gB0 + _ko, _d);                                \
        gload_lds16(gB0 + _ko + rowK16, _d + 1024);                \
    } while (0)

    // ---- read offsets (shorts): addr = AB + ROWb + quad-offset + pos[s] ----
    const int AROWb = (wm * 128 + lm) * 32;  // + mi*1024 (af0) / +2048+mi*1024 (af1)
    const int BROWb = (wn * 32 + lm) * 32;   // + qn*4096
    int pos[4];
#pragma unroll
    for (int s = 0; s < 4; ++s)
        pos[s] = (s >> 1) * 8192 + ((((s & 1) * 2 + hi) ^ key2) * 8);

    floatx16 acc[4][2];   // [m-tile][qn]
#pragma unroll
    for (int i = 0; i < 4; ++i)
#pragma unroll
        for (int j = 0; j < 2; ++j)
#pragma unroll
            for (int g = 0; g < 16; ++g)
                acc[i][j][g] = 0.f;

    short8 af0[2][4], af1[2][4], bf[2][4];   // [mi][s] / [qn][s]

    // early reads (next tile, from AB2): af0[mi][s01] + bf[0][s01]
#define READS_EARLY(AB2) do {                                              \
        _Pragma("unroll")                                                  \
        for (int mi = 0; mi < 2; ++mi) {                                   \
            af0[mi][0] = *(const short8*)&As[(AB2) + AROWb + mi * 1024 + pos[0]]; \
            af0[mi][1] = *(const short8*)&As[(AB2) + AROWb + mi * 1024 + pos[1]]; \
        }                                                                  \
        bf[0][0] = *(const short8*)&Bs[(AB2) + BROWb + pos[0]];            \
        bf[0][1] = *(const short8*)&Bs[(AB2) + BROWb + pos[1]];            \
    } while (0)

#define TILE_BODY(J, BUFC) do {                                            \
        constexpr int AB  = (BUFC) * 16384;                                \
        constexpr int AB2 = ((BUFC) ^ 1) * 16384;                          \
        /* -- P1: read af0 s23 + bf[1] s01; stage Bh1(J+1)->buf^1;      */ \
        /*    MFMA accs{0,1}x{0,1} s=0,1                                */ \
        _Pragma("unroll")                                                  \
        for (int mi = 0; mi < 2; ++mi) {                                   \
            af0[mi][2] = *(const short8*)&As[AB + AROWb + mi * 1024 + pos[2]]; \
            af0[mi][3] = *(const short8*)&As[AB + AROWb + mi * 1024 + pos[3]]; \
        }                                                                  \
        bf[1][0] = *(const short8*)&Bs[AB + BROWb + 4096 + pos[0]];        \
        bf[1][1] = *(const short8*)&Bs[AB + BROWb + 4096 + pos[1]];        \
        if ((J) + 1 < NT) STAGE_B((J) + 1, 1, (BUFC) ^ 1);                 \
        BAR();                                                             \
        __builtin_amdgcn_s_setprio(1);                                     \
        _Pragma("unroll")                                                  \
        for (int s = 0; s < 2; ++s) {                                      \
            acc[0][0] = MFMA_BF16(af0[0][s], bf[0][s], acc[0][0], 0, 0, 0);\
            acc[1][0] = MFMA_BF16(af0[1][s], bf[0][s], acc[1][0], 0, 0, 0);\
            acc[0][1] = MFMA_BF16(af0[0][s], bf[1][s], acc[0][1], 0, 0, 0);\
            acc[1][1] = MFMA_BF16(af0[1][s], bf[1][s], acc[1][1], 0, 0, 0);\
        }                                                                  \
        __builtin_amdgcn_s_setprio(0);                                     \
        asm volatile("s_waitcnt lgkmcnt(0)" ::: "memory");                 \
        BAR();                                                             \
        /* -- P2: read bf s23 (both qn) + af1 s01; stage Bh0(J+2)->buf; */ \
        /*    MFMA accs{0,1}x{0,1} s=2,3                                */ \
        bf[0][2] = *(const short8*)&Bs[AB + BROWb + pos[2]];               \
        bf[0][3] = *(const short8*)&Bs[AB + BROWb + pos[3]];               \
        bf[1][2] = *(const short8*)&Bs[AB + BROWb + 4096 + pos[2]];        \
        bf[1][3] = *(const short8*)&Bs[AB + BROWb + 4096 + pos[3]];        \
        _Pragma("unroll")                                                  \
        for (int mi = 0; mi < 2; ++mi) {                                   \
            af1[mi][0] = *(const short8*)&As[AB + AROWb + 2048 + mi * 1024 + pos[0]]; \
            af1[mi][1] = *(const short8*)&As[AB + AROWb + 2048 + mi * 1024 + pos[1]]; \
        }                                                                  \
        if ((J) + 2 < NT) STAGE_B((J) + 2, 0, (BUFC));                     \
        BAR();                                                             \
        __builtin_amdgcn_s_setprio(1);                                     \
        _Pragma("unroll")                                                  \
        for (int s = 2; s < 4; ++s) {                                      \
            acc[0][0] = MFMA_BF16(af0[0][s], bf[0][s], acc[0][0], 0, 0, 0);\
            acc[1][0] = MFMA_BF16(af0[1][s], bf[0][s], acc[1][0], 0, 0, 0);\
            acc[0][1] = MFMA_BF16(af0[0][s], bf[1][s], acc[0][1], 0, 0, 0);\
            acc[1][1] = MFMA_BF16(af0[1][s], bf[1][s], acc[1][1], 0, 0, 0);\
        }                                                                  \
        __builtin_amdgcn_s_setprio(0);                                     \
        asm volatile("s_waitcnt lgkmcnt(0)" ::: "memory");                 \
        BAR();                                                             \
        /* -- P3: read af1 s23; stage Ah0(J+2)->buf;                    */ \
        /*    MFMA accs{2,3}x{0,1} s=0,1                                */ \
        _Pragma("unroll")                                                  \
        for (int mi = 0; mi < 2; ++mi) {                                   \
            af1[mi][2] = *(const short8*)&As[AB + AROWb + 2048 + mi * 1024 + pos[2]]; \
            af1[mi][3] = *(const short8*)&As[AB + AROWb + 2048 + mi * 1024 + pos[3]]; \
        }                                                                  \
        if ((J) + 2 < NT) STAGE_A((J) + 2, 0, (BUFC));                     \
        BAR();                                                             \
        __builtin_amdgcn_s_setprio(1);                                     \
        _Pragma("unroll")                                                  \
        for (int s = 0; s < 2; ++s) {                                      \
            acc[2][0] = MFMA_BF16(af1[0][s], bf[0][s], acc[2][0], 0, 0, 0);\
            acc[3][0] = MFMA_BF16(af1[1][s], bf[0][s], acc[3][0], 0, 0, 0);\
            acc[2][1] = MFMA_BF16(af1[0][s], bf[1][s], acc[2][1], 0, 0, 0);\
            acc[3][1] = MFMA_BF16(af1[1][s], bf[1][s], acc[3][1], 0, 0, 0);\
        }                                                                  \
        __builtin_amdgcn_s_setprio(0);                                     \
        asm volatile("s_waitcnt lgkmcnt(0)" ::: "memory");                 \
        BAR();                                                             \
        /* -- P4: stage Ah1(J+2)->buf; vmcnt drain; BAR;                */ \
        /*    MFMA accs{2,3}x{0,1} s=2,3; THEN early reads (buf^1)      */ \
        if ((J) + 2 < NT) STAGE_A((J) + 2, 1, (BUFC));                     \
        if ((J) < NT - 2)       asm volatile("s_waitcnt vmcnt(6)" ::: "memory"); \
        else if ((J) == NT - 2) asm volatile("s_waitcnt vmcnt(0)" ::: "memory"); \
        BAR();                                                             \
        __builtin_amdgcn_s_setprio(1);                                     \
        _Pragma("unroll")                                                  \
        for (int s = 2; s < 4; ++s) {                                      \
            acc[2][0] = MFMA_BF16(af1[0][s], bf[0][s], acc[2][0], 0, 0, 0);\
            acc[3][0] = MFMA_BF16(af1[1][s], bf[0][s], acc[3][0], 0, 0, 0);\
            acc[2][1] = MFMA_BF16(af1[0][s], bf[1][s], acc[2][1], 0, 0, 0);\
            acc[3][1] = MFMA_BF16(af1[1][s], bf[1][s], acc[3][1], 0, 0, 0);\
        }                                                                  \
        __builtin_amdgcn_s_setprio(0);                                     \
        if ((J) + 1 < NT) READS_EARLY(AB2);                                \
        BAR();                                                             \
    } while (0)

    // ---- prologue: tile0 full + tile1 {Bh0,Ah0,Ah1}; drain tile0 ----
    STAGE_B(0, 0, 0); STAGE_A(0, 0, 0); STAGE_B(0, 1, 0); STAGE_A(0, 1, 0);
    STAGE_B(1, 0, 1); STAGE_A(1, 0, 1); STAGE_A(1, 1, 1);
    asm volatile("s_waitcnt vmcnt(6)" ::: "memory");
    BAR();
    READS_EARLY(0);   // tile0: af0 s01 + bf[0] s01 from buf0 (post-BAR: safe)

    for (int jj = 0; jj < NT; jj += 2) {
        TILE_BODY(jj, 0);
        TILE_BODY(jj + 1, 1);
    }
#undef STAGE_A
#undef STAGE_B
#undef READS_EARLY
#undef TILE_BODY

    // ---- epilogue: D layout col = lane&31 (n), row = (reg&3)+8*(reg>>2)+4*hi
    float bv[2];
#pragma unroll
    for (int n2 = 0; n2 < 2; ++n2)
        bv[n2] = HESS ? 0.f : bias[bn + n2 * 128 + wn * 32 + lm];
#pragma unroll
    for (int m4 = 0; m4 < 4; ++m4) {
        const size_t mbase = bm + wm * 128 + m4 * 32 + 4 * hi;
#pragma unroll
        for (int n2 = 0; n2 < 2; ++n2) {
            const size_t n = bn + n2 * 128 + wn * 32 + lm;
#pragma unroll
            for (int reg = 0; reg < 16; ++reg) {
                const size_t m = mbase + (reg & 3) + 8 * (reg >> 2);
                float v = acc[m4][n2][reg] + bv[n2];
                if (HESS && m == n) v += 1e-4f;
                C[m * N + n] = v;
            }
        }
    }
}

extern "C" void kernel_launch(void* const* d_in, const int* in_sizes, int n_in,
                              void* d_out, int out_size, void* d_ws, size_t ws_size,
                              hipStream_t stream) {
    const float* x = (const float*)d_in[0];   // [8192, 4096]
    const float* W = (const float*)d_in[1];   // [4096, 4096]
    const float* b = (const float*)d_in[2];   // [4096]

    float* out  = (float*)d_out;                       // [8192, 4096]
    float* hess = out + (size_t)BDIM * DOUTD;          // [4096, 4096]

    // workspace layout (bf16): xb [B,D] | xT [D,B] | Wb [DOUT,D]  = 168 MB
    unsigned short* xb = (unsigned short*)d_ws;
    unsigned short* xT = xb + (size_t)BDIM * DDIM;
    unsigned short* Wb = xT + (size_t)BDIM * DDIM;

    convert_transpose_x<<<dim3(BDIM / 64, DDIM / 64), 256, 0, stream>>>(x, xb, xT);
    convert_w_kernel<<<((size_t)DOUTD * DDIM) / 2048, 256, 0, stream>>>(W, Wb);

    // out = x @ W.T + b : M=8192, N=4096, K=4096  (grid 16 x 32 = 512 blocks)
    gemm256<false><<<dim3(DOUTD / 256, BDIM / 256), 512, 0, stream>>>(
        xb, Wb, b, out, BDIM, DOUTD, DDIM);
    // hess = xT @ xT.T + eps*I : M=N=4096, K=8192  (grid 16 x 16 = 256 blocks)
    gemm256<true><<<dim3(DDIM / 256, DDIM / 256), 512, 0, stream>>>(
        xT, xT, nullptr, hess, DDIM, DDIM, BDIM);
}